// Round 15
// baseline (2050.211 us; speedup 1.0000x reference)
//
#include <hip/hip_runtime.h>

#define T_STEPS 256
#define BATCH   128
#define OBSD    512
#define HID     1024
#define GH      4096
#define ACTD    18
#define TBROWS  (T_STEPS*BATCH)   // 32768
#define SNWG    1024              // scan WGs: 8 batch-eighths x 128 j-slices
#define JG      8                 // hidden units per scan WG

typedef __bf16 bf16x8_t __attribute__((ext_vector_type(8)));
typedef float  f32x4_t  __attribute__((ext_vector_type(4)));

__device__ __forceinline__ ushort f2bf(float f) {
  unsigned u = __builtin_bit_cast(unsigned, f);
  u += 0x7fffu + ((u >> 16) & 1u);          // RNE
  return (ushort)(u >> 16);
}
__device__ __forceinline__ float bf2f(ushort s) {
  return __builtin_bit_cast(float, ((unsigned)s) << 16);
}
__device__ __forceinline__ f32x4_t mfma16(bf16x8_t a, bf16x8_t b, f32x4_t c) {
  return __builtin_amdgcn_mfma_f32_16x16x32_bf16(a, b, c, 0, 0, 0);
}
__device__ __forceinline__ void gl_lds16(const void* g, void* l) {
  __builtin_amdgcn_global_load_lds(
      (__attribute__((address_space(1))) void*)(g),
      (__attribute__((address_space(3))) void*)(l), 16, 0, 0);
}
__device__ __forceinline__ float sigm(float x) { return 1.f / (1.f + __expf(-x)); }
__device__ __forceinline__ float tanhf_fast(float x) {
  float e = __expf(2.f * x);
  return (e - 1.f) / (e + 1.f);
}
// vmcnt-only wait (lgkm=15/exp=7 fields = no-wait)
#define WAITVM(N) __builtin_amdgcn_s_waitcnt(0x0F70 | ((N) & 15))
__device__ __forceinline__ void wait_vm0() { __builtin_amdgcn_s_waitcnt(0x0F70); }

// ---------------- cast f32 -> bf16 ----------------
__global__ void cast_bf16_kernel(const float* __restrict__ in, ushort* __restrict__ out, int n4) {
  int i = blockIdx.x * blockDim.x + threadIdx.x;
  int stride = gridDim.x * blockDim.x;
  for (; i < n4; i += stride) {
    float4 v = reinterpret_cast<const float4*>(in)[i];
    ushort4 o;
    o.x = f2bf(v.x); o.y = f2bf(v.y); o.z = f2bf(v.z); o.w = f2bf(v.w);
    reinterpret_cast<ushort4*>(out)[i] = o;
  }
}

// ---------------- cast+permute W_ih: dst row hid*4+g <- src row g*HID+hid ----------------
__global__ void cast_permute_wih_kernel(const float* __restrict__ in, ushort* __restrict__ out) {
  int idx = blockIdx.x * 256 + threadIdx.x;     // over 4096 * 128
  int rowd = idx >> 7;
  int c8 = (idx & 127) << 3;
  int g = rowd & 3, hid = rowd >> 2;
  const float* src = in + ((size_t)g * HID + hid) * HID + c8;
  ushort* dst = out + (size_t)rowd * HID + c8;
#pragma unroll
  for (int i = 0; i < 8; ++i) dst[i] = f2bf(src[i]);
}

// ---------------- bias permute: out[hid*4+g] = bih[g*H+hid] + bhh[g*H+hid] ----------------
__global__ void bias_perm_kernel(const float* __restrict__ bih, const float* __restrict__ bhh,
                                 float* __restrict__ out) {
  int i = blockIdx.x * 256 + threadIdx.x;       // 4096
  int g = i & 3, hid = i >> 2;
  out[i] = bih[g * HID + hid] + bhh[g * HID + hid];
}

// ---------------- m97 128x128 GEMM (kept for decode: N=128) ----------------
__global__ __launch_bounds__(256) void gemm_bt_kernel(
    const ushort* __restrict__ A, const ushort* __restrict__ Bt,
    const float* __restrict__ bias1,
    ushort* __restrict__ C, int M, int N, int K, int relu,
    const int* __restrict__ omask, float* __restrict__ ovals)
{
  __shared__ ushort la[128 * 64];   // 16 KB
  __shared__ ushort lb[128 * 64];   // 16 KB

  const int tid  = threadIdx.x;
  const int lane = tid & 63;
  const int w    = tid >> 6;
  const int wm   = w >> 1, wn = w & 1;
  const int nwg = gridDim.x;
  const int q8  = nwg >> 3;
  const int bid = (blockIdx.x & 7) * q8 + (blockIdx.x >> 3);
  const int ntiles = N >> 7;
  const int bm = bid / ntiles, bn = bid % ntiles;
  const size_t m0 = (size_t)bm << 7, n0 = (size_t)bn << 7;

  const int lrow = lane & 15;
  const int lk   = (lane >> 4) << 3;
  const int wavebase = (tid & ~63);

  f32x4_t acc[4][4];
  const f32x4_t zero = {0.f, 0.f, 0.f, 0.f};
#pragma unroll
  for (int i = 0; i < 4; ++i)
#pragma unroll
    for (int j = 0; j < 4; ++j) acc[i][j] = zero;

  for (int k0 = 0; k0 < K; k0 += 64) {
#pragma unroll
    for (int p = 0; p < 4; ++p) {
      int c = p * 256 + tid;
      int r = c >> 3;
      int q = (c & 7) << 3;
      gl_lds16(A + (m0 + r) * (size_t)K + k0 + q, la + (size_t)(p * 256 + wavebase) * 8);
      gl_lds16(Bt + (n0 + r) * (size_t)K + k0 + q, lb + (size_t)(p * 256 + wavebase) * 8);
    }
    __syncthreads();
#pragma unroll
    for (int kk = 0; kk < 64; kk += 32) {
      bf16x8_t af[4], bfr[4];
#pragma unroll
      for (int i = 0; i < 4; ++i)
        af[i] = *(const bf16x8_t*)(la + (wm * 64 + i * 16 + lrow) * 64 + kk + lk);
#pragma unroll
      for (int j = 0; j < 4; ++j)
        bfr[j] = *(const bf16x8_t*)(lb + (wn * 64 + j * 16 + lrow) * 64 + kk + lk);
#pragma unroll
      for (int i = 0; i < 4; ++i)
#pragma unroll
        for (int j = 0; j < 4; ++j)
          acc[i][j] = mfma16(af[i], bfr[j], acc[i][j]);
    }
    __syncthreads();
  }

  const int crow0 = (lane >> 4) * 4;
  if (ovals) {
#pragma unroll
    for (int j = 0; j < 4; ++j) {
      int col = wn * 64 + j * 16 + lrow;
      if (col < ACTD) {
        float bv = bias1[col];
#pragma unroll
        for (int i = 0; i < 4; ++i) {
#pragma unroll
          for (int r = 0; r < 4; ++r) {
            size_t row = m0 + wm * 64 + i * 16 + crow0 + r;
            float mv = (float)omask[row];
            ovals[row * ACTD + col] = (acc[i][j][r] + bv) * mv;
          }
        }
      }
    }
    return;
  }
#pragma unroll
  for (int j = 0; j < 4; ++j) {
    int col = (int)n0 + wn * 64 + j * 16 + lrow;
    float bv = bias1 ? bias1[col] : 0.f;
#pragma unroll
    for (int i = 0; i < 4; ++i) {
#pragma unroll
      for (int r = 0; r < 4; ++r) {
        size_t row = m0 + wm * 64 + i * 16 + crow0 + r;
        float v = acc[i][j][r] + bv;
        if (relu) v = fmaxf(v, 0.f);
        C[row * (size_t)N + col] = f2bf(v);
      }
    }
  }
}

// ---------------- 256x256 8-wave double-buffered GEMM (r12-proven) ----------------
__global__ __launch_bounds__(512, 2) void gemm256_kernel(
    const ushort* __restrict__ A, const ushort* __restrict__ Bt,
    const float* __restrict__ bias,
    ushort* __restrict__ C, int M, int N, int K, int relu)
{
  __shared__ __align__(16) ushort lds[2][2][16384];   // [buf][A/B][256*64] = 128 KB

  const int tid  = threadIdx.x;
  const int lane = tid & 63;
  const int wid  = tid >> 6;            // 0..7
  const int wm   = wid >> 2, wn = wid & 3;
  const int nwg  = gridDim.x;           // multiple of 8
  const int q8   = nwg >> 3;
  const int bid  = (blockIdx.x & 7) * q8 + (blockIdx.x >> 3);   // XCD swizzle
  const int ntiles = N >> 8;
  const int bm = bid / ntiles, bn = bid % ntiles;
  const size_t m0 = (size_t)bm << 8, n0 = (size_t)bn << 8;

  const int lrow = lane & 15;
  const int lkg  = lane >> 4;

  int srow[4], sgsr[4];
#pragma unroll
  for (int q = 0; q < 4; ++q) {
    int s = (q * 8 + wid) * 64 + lane;
    srow[q] = s >> 3;
    sgsr[q] = (s & 7) ^ ((s >> 3) & 7);
  }

#define STAGE256(BUF, KT) do {                                                \
    const size_t kb_ = (size_t)(KT) * 64;                                     \
    _Pragma("unroll")                                                         \
    for (int q = 0; q < 4; ++q) {                                             \
      gl_lds16(A  + (m0 + srow[q]) * (size_t)K + kb_ + sgsr[q] * 8,           \
               &lds[BUF][0][(q * 8 + wid) * 512]);                            \
      gl_lds16(Bt + (n0 + srow[q]) * (size_t)K + kb_ + sgsr[q] * 8,           \
               &lds[BUF][1][(q * 8 + wid) * 512]);                            \
    }                                                                         \
  } while (0)

  f32x4_t acc[8][4];
  const f32x4_t zero = {0.f, 0.f, 0.f, 0.f};
#pragma unroll
  for (int f = 0; f < 8; ++f)
#pragma unroll
    for (int n = 0; n < 4; ++n) acc[f][n] = zero;

  const int nkt = K >> 6;
  STAGE256(0, 0);
  STAGE256(1, 1);

  for (int kt = 0; kt < nkt; ++kt) {
    const int buf = kt & 1;
    if (kt + 1 < nkt) WAITVM(8); else WAITVM(0);   // K-tile kt resident
    __builtin_amdgcn_s_barrier();
    __builtin_amdgcn_sched_barrier(0);
#pragma unroll
    for (int p = 0; p < 4; ++p) {
      const int kk = p >> 1, mg = p & 1;
      bf16x8_t av[4], bv[4];
#pragma unroll
      for (int f = 0; f < 4; ++f) {
        int ar = wm * 128 + (mg * 4 + f) * 16 + lrow;
        int ags = (kk * 4 + lkg) ^ (ar & 7);
        av[f] = *(const bf16x8_t*)&lds[buf][0][ar * 64 + ags * 8];
      }
#pragma unroll
      for (int n = 0; n < 4; ++n) {
        int br = wn * 64 + n * 16 + lrow;
        int bgs = (kk * 4 + lkg) ^ (br & 7);
        bv[n] = *(const bf16x8_t*)&lds[buf][1][br * 64 + bgs * 8];
      }
      __builtin_amdgcn_s_setprio(1);
#pragma unroll
      for (int f = 0; f < 4; ++f)
#pragma unroll
        for (int n = 0; n < 4; ++n)
          acc[mg * 4 + f][n] = mfma16(av[f], bv[n], acc[mg * 4 + f][n]);
      __builtin_amdgcn_s_setprio(0);
    }
    __builtin_amdgcn_s_barrier();        // all waves done reading buf
    if (kt + 2 < nkt) STAGE256(buf, kt + 2);
  }
#undef STAGE256

  const int crow0 = lkg * 4;
#pragma unroll
  for (int n = 0; n < 4; ++n) {
    int col = (int)n0 + wn * 64 + n * 16 + lrow;
    float bvv = bias ? bias[col] : 0.f;
#pragma unroll
    for (int f = 0; f < 8; ++f) {
#pragma unroll
      for (int r = 0; r < 4; ++r) {
        size_t row = m0 + (size_t)wm * 128 + f * 16 + crow0 + r;
        float v = acc[f][n][r] + bvv;
        if (relu) v = fmaxf(v, 0.f);
        C[row * (size_t)N + col] = f2bf(v);
      }
    }
  }
}

// ---------------- persistent LSTM scan, 128-thread WG (r15) ----------------
// 1024 WGs = 8 batch-eighths (16 rows) x 128 j-slices (8 hidden). 2 waves/WG,
// LDS ~33 KB -> 4 WGs/CU from 4 DIFFERENT eighths = 4 independent latency chains
// per CU (r14 had 2). All staging/consume/fragment formulas identical to r14;
// only slot->thread (2 slots/thread), W-gather (2x16-row passes), flags
// (128/eighth, wave0 polls 2 each) and epilogue width (128 cells) change.
__global__ __launch_bounds__(128, 2) void lstm_scan_kernel(
    const ushort* __restrict__ xg,      // (nsteps,B,4H) bf16, gate-permuted
    const ushort* __restrict__ whh,     // (4H,H) bf16 natural
    const int* __restrict__ mask,       // (nsteps,B) (pre-offset)
    const ushort* __restrict__ hinit,   // (B,H) bf16 zeros (h at t=-1)
    ushort* __restrict__ hseq,          // (T,B,H) bf16: h(t) = latent
    float* __restrict__ cbuf,           // (B,H) f32 persistent cell state
    float* __restrict__ outh, float* __restrict__ outc,   // (B,H) f32
    unsigned* __restrict__ flags,       // 1024 x 16 uints, zeroed per launch
    int t0, int nsteps)
{
  __shared__ __align__(16) ushort pool[16 * 1024];  // 32 KB: W gather window, then 8x4KB staging
  __shared__ __align__(16) ushort hexch[16 * 8];    // 0.25 KB h bounce

  const int tid  = threadIdx.x;
  const int lane = tid & 63;
  const int w    = tid >> 6;           // 0..1
  const int wg   = blockIdx.x;
  const int eg   = wg >> 7;            // batch eighth 0..7
  const int jg   = wg & 127;           // j slice 0..127
  const int j0   = jg * JG;
  const int b0   = eg * 16;

  const int lrow = lane & 15;
  const int lkg  = lane >> 4;

  // ---- W gather: 2 passes of 16 gate rows through the 32 KB window ----
  // WG's gate rows rr = jj*4+g (0..31), jj in [0,8). Wave w owns rr in [16w,16w+16).
  bf16x8_t af[8][4];
#pragma unroll 1
  for (int p = 0; p < 2; ++p) {
    for (int c = tid; c < 16 * 128; c += 128) {
      int rl = c >> 7, gn = c & 127;
      int rr = p * 16 + rl;
      int jj = rr >> 2, g = rr & 3;
      const ushort* src = whh + ((size_t)g * HID + j0 + jj) * HID + gn * 8;
      int gnd = (gn & ~7) | ((gn & 7) ^ (rl & 7));
      *reinterpret_cast<uint4*>(&pool[rl * 1024 + gnd * 8]) =
          *reinterpret_cast<const uint4*>(src);
    }
    __syncthreads();
    if (w == p) {
#pragma unroll
      for (int kc = 0; kc < 8; ++kc)
#pragma unroll
        for (int ks = 0; ks < 4; ++ks) {
          int gA = kc * 16 + ks * 4 + lkg;
          int gAs = (gA & ~7) | ((gA & 7) ^ (lrow & 7));
          af[kc][ks] = *(const bf16x8_t*)(pool + (size_t)lrow * 1024 + gAs * 8);
        }
    }
    __syncthreads();
  }

  // cell mapping: thread owns (batch row bl0 = lrow, hidden jjc = w*4+lkg in [0,8))
  const int jjc = w * 4 + lkg;
  const int bl0 = lrow;

  float creg;
  if (t0 == 0) creg = 0.f;
  else creg = cbuf[(size_t)(b0 + bl0) * HID + j0 + jjc];

  // staging constants: 2 slots/thread: s_q = q*128 + w*64 + lane (q=0,1)
  int sbq[2], ggq[2];
#pragma unroll
  for (int q = 0; q < 2; ++q) {
    int s = q * 128 + w * 64 + lane;
    int sb = s >> 4, sq = s & 15;
    sbq[q] = sb;
    ggq[q] = (sq & 8) | ((sq & 7) ^ (sb & 7));
  }

  // per-eighth flags (128 j-slices); wave0 lane i polls flags i and i+64
  unsigned* myflag = flags + (size_t)(eg * 128 + jg) * 16;
  const unsigned* fp0 = flags + (size_t)(eg * 128 + lane) * 16;
  const unsigned* fp1 = flags + (size_t)(eg * 128 + 64 + lane) * 16;

  // prefetch xg/mask for step 0
  ushort4 xv;
  float mv;
  {
    xv = *(const ushort4*)(xg + (size_t)(b0 + bl0) * GH + (j0 + jjc) * 4);
    mv = (float)mask[b0 + bl0];
  }
  __builtin_amdgcn_sched_barrier(0);

#define CHUNK(KC) do {                                                         \
    WAITVM(14 - 2 * (KC));                                                     \
    __builtin_amdgcn_s_barrier();                                              \
    __builtin_amdgcn_sched_barrier(0);                                         \
    const ushort* sbuf = pool + (size_t)(KC) * 2048;                           \
    _Pragma("unroll")                                                          \
    for (int ks = 0; ks < 4; ++ks) {                                           \
      int q16 = ks * 4 + lkg;                                                  \
      int qs = (q16 & 8) | ((q16 & 7) ^ (bl0 & 7));                            \
      bf16x8_t bv = *(const bf16x8_t*)(sbuf + (size_t)bl0 * 128 + qs * 8);     \
      acc = mfma16(af[KC][ks], bv, acc);                                       \
    }                                                                          \
    __builtin_amdgcn_sched_barrier(0);                                         \
  } while (0)

  for (int tl = 0; tl < nsteps; ++tl) {
    const int gs = t0 + tl;
    const ushort* hsrc = (gs == 0)
        ? (hinit + (size_t)b0 * HID)
        : (hseq + (size_t)(gs - 1) * (BATCH * HID) + (size_t)b0 * HID);

    wait_vm0();                          // clean vmcnt slate (prefetch drained)
    __builtin_amdgcn_sched_barrier(0);

    f32x4_t acc = {0.f, 0.f, 0.f, 0.f};

    // issue all 16 cached staging loads (8 chunks x 2 slots) back-to-back
#pragma unroll
    for (int kc = 0; kc < 8; ++kc) {
      gl_lds16(hsrc + (size_t)sbq[0] * HID + (kc * 16 + ggq[0]) * 8,
               pool + (size_t)kc * 2048 + (size_t)(w * 64) * 8);
      gl_lds16(hsrc + (size_t)sbq[1] * HID + (kc * 16 + ggq[1]) * 8,
               pool + (size_t)kc * 2048 + (size_t)(128 + w * 64) * 8);
    }
    __builtin_amdgcn_sched_barrier(0);

    CHUNK(0); CHUNK(1); CHUNK(2); CHUNK(3);
    CHUNK(4); CHUNK(5); CHUNK(6); CHUNK(7);

    // ---- epilogue: fragment-native nonlinearities (thread owns 1 cell) ----
    {
      float ig = sigm(acc[0] + bf2f(xv.x));
      float fg = sigm(acc[1] + bf2f(xv.y));
      float gt = tanhf_fast(acc[2] + bf2f(xv.z));
      float og = sigm(acc[3] + bf2f(xv.w));
      float cp = fg * creg + ig * gt;
      creg = cp * mv;
      float h = og * tanhf_fast(cp) * mv;
      hexch[bl0 * 8 + jjc] = f2bf(h);
      if (gs == T_STEPS - 1) {
        outh[(size_t)(b0 + bl0) * HID + j0 + jjc] = h;
        outc[(size_t)(b0 + bl0) * HID + j0 + jjc] = creg;
      }
    }
    __syncthreads();                     // hexch complete; pool reads done

    // device-coherent 8B h stores into hseq[t] (write-through LLC, no fence)
    if (tid < 32) {
      int bl = tid >> 1, seg = tid & 1;
      unsigned long long v = *(const unsigned long long*)(&hexch[bl * 8 + seg * 4]);
      unsigned long long* dst = (unsigned long long*)(hseq +
          (size_t)gs * (BATCH * HID) + (size_t)(b0 + bl) * HID + j0 + seg * 4);
      __hip_atomic_store(dst, v, __ATOMIC_RELAXED, __HIP_MEMORY_SCOPE_AGENT);
    }

    // ---- per-eighth flat depth-1 barrier (skip after last local step) ----
    if (tl != nsteps - 1) {
      __syncthreads();                   // all h stores complete (vmcnt0/wave)
      const unsigned tgt = (unsigned)(gs + 1);
      if (tid == 0)
        __hip_atomic_store(myflag, tgt, __ATOMIC_RELAXED, __HIP_MEMORY_SCOPE_AGENT);
      // overlap: prefetch next step's xg + mask (immutable -> staleness ok)
      {
        const ushort* xp = xg + (size_t)(tl + 1) * BATCH * GH;
        xv = *(const ushort4*)(xp + (size_t)(b0 + bl0) * GH + (j0 + jjc) * 4);
        mv = (float)mask[(tl + 1) * BATCH + b0 + bl0];
      }
      __builtin_amdgcn_sched_barrier(0);
      // wave0: lane i polls its eighth's flags i and i+64
      if (tid < 64) {
        for (;;) {
          unsigned v0 = __hip_atomic_load(fp0, __ATOMIC_RELAXED, __HIP_MEMORY_SCOPE_AGENT);
          unsigned v1 = __hip_atomic_load(fp1, __ATOMIC_RELAXED, __HIP_MEMORY_SCOPE_AGENT);
          if (__all(v0 >= tgt && v1 >= tgt)) break;
        }
      }
      __syncthreads();
    }
  }
#undef CHUNK

  // persist cell state for next chunk
  cbuf[(size_t)(b0 + bl0) * HID + j0 + jjc] = creg;
}

extern "C" void kernel_launch(void* const* d_in, const int* in_sizes, int n_in,
                              void* d_out, int out_size, void* d_ws, size_t ws_size,
                              hipStream_t stream) {
  (void)in_sizes; (void)n_in; (void)out_size;
  const float* state = (const float*)d_in[0];
  const int*   mask  = (const int*)d_in[1];
  const float* Wenc  = (const float*)d_in[2];
  const float* benc  = (const float*)d_in[3];
  const float* Wih   = (const float*)d_in[4];
  const float* Whh   = (const float*)d_in[5];
  const float* bih   = (const float*)d_in[6];
  const float* bhh   = (const float*)d_in[7];
  const float* Wdec  = (const float*)d_in[8];
  const float* bdec  = (const float*)d_in[9];

  float* out_values = (float*)d_out;                       // T*B*A
  float* out_h = out_values + (size_t)TBROWS * ACTD;       // B*H
  float* out_c = out_h + (size_t)BATCH * HID;              // B*H

  auto pad256 = [](size_t b) { return (b + 255) & ~(size_t)255; };

  const size_t sz_wenc  = (size_t)HID * OBSD * 2;
  const size_t sz_wih   = (size_t)GH * HID * 2;
  const size_t sz_whh   = (size_t)GH * HID * 2;
  const size_t sz_wdec  = (size_t)128 * HID * 2;
  const size_t sz_bdec  = 512;
  const size_t sz_bperm = (size_t)GH * sizeof(float);
  const size_t sz_flags = (size_t)SNWG * 16 * sizeof(unsigned);   // 64 KB
  const size_t sz_hseq  = (size_t)TBROWS * HID * 2;        // 64 MiB: h(t) = latent
  const size_t sz_hinit = (size_t)BATCH * HID * 2;         // zeros
  const size_t sz_cbuf  = (size_t)BATCH * HID * 4;
  const size_t fixed = pad256(sz_wenc) + pad256(sz_wih) + pad256(sz_whh) +
                       pad256(sz_wdec) + pad256(sz_bdec) + pad256(sz_bperm) +
                       pad256(sz_flags) + pad256(sz_hseq) + pad256(sz_hinit) +
                       pad256(sz_cbuf);

  // largest Tc that fits. enc_c aliases the hseq chunk region (encode->xg lifetime
  // strictly precedes scan's overwrite of hseq[t0..t0+Tc)); state_c aliases xg_c.
  // So per-chunk extra = xg only.
  int Tc = 8;
  {
    const int cands[6] = {256, 128, 64, 32, 16, 8};
    for (int ci = 0; ci < 6; ++ci) {
      int tc = cands[ci];
      size_t per = pad256((size_t)tc * BATCH * GH * 2);       // xg chunk
      if (fixed + per <= ws_size) { Tc = tc; break; }
    }
  }
  const int nchunks = T_STEPS / Tc;
  const int crows = Tc * BATCH;

  char* ws = (char*)d_ws;
  size_t off = 0;
  auto alloc = [&](size_t b) { char* r = ws + off; off += pad256(b); return r; };
  ushort* wenc_bf  = (ushort*)alloc(sz_wenc);
  ushort* wih_perm = (ushort*)alloc(sz_wih);
  ushort* whh_bf   = (ushort*)alloc(sz_whh);
  ushort* wdec_pad = (ushort*)alloc(sz_wdec);
  float*  bdec_pad = (float*)alloc(sz_bdec);
  float*  bperm    = (float*)alloc(sz_bperm);
  unsigned* flags  = (unsigned*)alloc(sz_flags);
  ushort* hseq     = (ushort*)alloc(sz_hseq);
  ushort* hinit    = (ushort*)alloc(sz_hinit);
  float*  cbuf     = (float*)alloc(sz_cbuf);
  ushort* xg_c     = (ushort*)alloc((size_t)crows * GH * 2);
  ushort* state_c  = xg_c;               // alias: dead before xg GEMM writes

  hipMemsetAsync(hinit, 0, sz_hinit, stream);
  hipMemsetAsync(flags, 0, sz_flags, stream);
  hipMemsetAsync(wdec_pad, 0, sz_wdec, stream);
  hipMemsetAsync(bdec_pad, 0, sz_bdec, stream);
  hipMemcpyAsync(bdec_pad, bdec, ACTD * sizeof(float), hipMemcpyDeviceToDevice, stream);

  auto cast = [&](const float* src, ushort* dst, size_t n) {
    int n4 = (int)(n / 4);
    int blocks = (n4 + 255) / 256;
    if (blocks > 4096) blocks = 4096;
    cast_bf16_kernel<<<blocks, 256, 0, stream>>>(src, dst, n4);
  };
  cast(Wenc, wenc_bf, (size_t)HID * OBSD);
  cast(Whh, whh_bf, (size_t)GH * HID);
  cast(Wdec, wdec_pad, (size_t)ACTD * HID);
  cast_permute_wih_kernel<<<(GH * 128) / 256, 256, 0, stream>>>(Wih, wih_perm);
  bias_perm_kernel<<<GH / 256, 256, 0, stream>>>(bih, bhh, bperm);

  for (int c = 0; c < nchunks; ++c) {
    const int t0 = c * Tc;
    ushort* enc_c = hseq + (size_t)t0 * BATCH * HID;   // alias hseq chunk region
    cast(state + (size_t)t0 * BATCH * OBSD, state_c, (size_t)crows * OBSD);
    // encode: relu(state @ Wenc^T + b_enc)  [256^2 8-wave GEMM]
    gemm256_kernel<<<(crows / 256) * (HID / 256), 512, 0, stream>>>(
        state_c, wenc_bf, benc, enc_c, crows, HID, OBSD, 1);
    // x-gates (gate-permuted cols): enc @ Wih_perm^T + bperm  [256^2 8-wave GEMM]
    gemm256_kernel<<<(crows / 256) * (GH / 256), 512, 0, stream>>>(
        enc_c, wih_perm, bperm, xg_c, crows, GH, HID, 0);
    // sequential scan over this chunk (overwrites hseq[t0 .. t0+Tc))
    lstm_scan_kernel<<<SNWG, 128, 0, stream>>>(
        xg_c, whh_bf, mask + (size_t)t0 * BATCH, hinit, hseq, cbuf,
        out_h, out_c, flags, t0, Tc);
  }

  // single full-machine decode + mask + extract over ALL timesteps (grid = 256)
  gemm_bt_kernel<<<TBROWS / 128, 256, 0, stream>>>(
      hseq, wdec_pad, bdec_pad, nullptr, TBROWS, 128, HID, 0,
      mask, out_values);
}

// Round 16
// 1296.665 us; speedup vs baseline: 1.5811x; 1.5811x over previous
//
#include <hip/hip_runtime.h>

#define T_STEPS 256
#define BATCH   128
#define OBSD    512
#define HID     1024
#define GH      4096
#define ACTD    18
#define TBROWS  (T_STEPS*BATCH)   // 32768
#define SNWG    512               // scan WGs: 8 batch-eighths x 64 j-slices
#define JG      16                // hidden units per scan WG

typedef __bf16 bf16x8_t __attribute__((ext_vector_type(8)));
typedef float  f32x4_t  __attribute__((ext_vector_type(4)));

__device__ __forceinline__ ushort f2bf(float f) {
  unsigned u = __builtin_bit_cast(unsigned, f);
  u += 0x7fffu + ((u >> 16) & 1u);          // RNE
  return (ushort)(u >> 16);
}
__device__ __forceinline__ float bf2f(ushort s) {
  return __builtin_bit_cast(float, ((unsigned)s) << 16);
}
__device__ __forceinline__ f32x4_t mfma16(bf16x8_t a, bf16x8_t b, f32x4_t c) {
  return __builtin_amdgcn_mfma_f32_16x16x32_bf16(a, b, c, 0, 0, 0);
}
__device__ __forceinline__ void gl_lds16(const void* g, void* l) {
  __builtin_amdgcn_global_load_lds(
      (__attribute__((address_space(1))) void*)(g),
      (__attribute__((address_space(3))) void*)(l), 16, 0, 0);
}
__device__ __forceinline__ float sigm(float x) { return 1.f / (1.f + __expf(-x)); }
__device__ __forceinline__ float tanhf_fast(float x) {
  float e = __expf(2.f * x);
  return (e - 1.f) / (e + 1.f);
}
// vmcnt-only wait (lgkm=15/exp=7 fields = no-wait)
#define WAITVM(N) __builtin_amdgcn_s_waitcnt(0x0F70 | ((N) & 15))
__device__ __forceinline__ void wait_vm0() { __builtin_amdgcn_s_waitcnt(0x0F70); }

// ---------------- cast f32 -> bf16 ----------------
__global__ void cast_bf16_kernel(const float* __restrict__ in, ushort* __restrict__ out, int n4) {
  int i = blockIdx.x * blockDim.x + threadIdx.x;
  int stride = gridDim.x * blockDim.x;
  for (; i < n4; i += stride) {
    float4 v = reinterpret_cast<const float4*>(in)[i];
    ushort4 o;
    o.x = f2bf(v.x); o.y = f2bf(v.y); o.z = f2bf(v.z); o.w = f2bf(v.w);
    reinterpret_cast<ushort4*>(out)[i] = o;
  }
}

// ---------------- cast+permute W_ih: dst row hid*4+g <- src row g*HID+hid ----------------
__global__ void cast_permute_wih_kernel(const float* __restrict__ in, ushort* __restrict__ out) {
  int idx = blockIdx.x * 256 + threadIdx.x;     // over 4096 * 128
  int rowd = idx >> 7;
  int c8 = (idx & 127) << 3;
  int g = rowd & 3, hid = rowd >> 2;
  const float* src = in + ((size_t)g * HID + hid) * HID + c8;
  ushort* dst = out + (size_t)rowd * HID + c8;
#pragma unroll
  for (int i = 0; i < 8; ++i) dst[i] = f2bf(src[i]);
}

// ---------------- bias permute: out[hid*4+g] = bih[g*H+hid] + bhh[g*H+hid] ----------------
__global__ void bias_perm_kernel(const float* __restrict__ bih, const float* __restrict__ bhh,
                                 float* __restrict__ out) {
  int i = blockIdx.x * 256 + threadIdx.x;       // 4096
  int g = i & 3, hid = i >> 2;
  out[i] = bih[g * HID + hid] + bhh[g * HID + hid];
}

// ---------------- m97 128x128 GEMM (kept for decode: N=128) ----------------
__global__ __launch_bounds__(256) void gemm_bt_kernel(
    const ushort* __restrict__ A, const ushort* __restrict__ Bt,
    const float* __restrict__ bias1,
    ushort* __restrict__ C, int M, int N, int K, int relu,
    const int* __restrict__ omask, float* __restrict__ ovals)
{
  __shared__ ushort la[128 * 64];   // 16 KB
  __shared__ ushort lb[128 * 64];   // 16 KB

  const int tid  = threadIdx.x;
  const int lane = tid & 63;
  const int w    = tid >> 6;
  const int wm   = w >> 1, wn = w & 1;
  const int nwg = gridDim.x;
  const int q8  = nwg >> 3;
  const int bid = (blockIdx.x & 7) * q8 + (blockIdx.x >> 3);
  const int ntiles = N >> 7;
  const int bm = bid / ntiles, bn = bid % ntiles;
  const size_t m0 = (size_t)bm << 7, n0 = (size_t)bn << 7;

  const int lrow = lane & 15;
  const int lk   = (lane >> 4) << 3;
  const int wavebase = (tid & ~63);

  f32x4_t acc[4][4];
  const f32x4_t zero = {0.f, 0.f, 0.f, 0.f};
#pragma unroll
  for (int i = 0; i < 4; ++i)
#pragma unroll
    for (int j = 0; j < 4; ++j) acc[i][j] = zero;

  for (int k0 = 0; k0 < K; k0 += 64) {
#pragma unroll
    for (int p = 0; p < 4; ++p) {
      int c = p * 256 + tid;
      int r = c >> 3;
      int q = (c & 7) << 3;
      gl_lds16(A + (m0 + r) * (size_t)K + k0 + q, la + (size_t)(p * 256 + wavebase) * 8);
      gl_lds16(Bt + (n0 + r) * (size_t)K + k0 + q, lb + (size_t)(p * 256 + wavebase) * 8);
    }
    __syncthreads();
#pragma unroll
    for (int kk = 0; kk < 64; kk += 32) {
      bf16x8_t af[4], bfr[4];
#pragma unroll
      for (int i = 0; i < 4; ++i)
        af[i] = *(const bf16x8_t*)(la + (wm * 64 + i * 16 + lrow) * 64 + kk + lk);
#pragma unroll
      for (int j = 0; j < 4; ++j)
        bfr[j] = *(const bf16x8_t*)(lb + (wn * 64 + j * 16 + lrow) * 64 + kk + lk);
#pragma unroll
      for (int i = 0; i < 4; ++i)
#pragma unroll
        for (int j = 0; j < 4; ++j)
          acc[i][j] = mfma16(af[i], bfr[j], acc[i][j]);
    }
    __syncthreads();
  }

  const int crow0 = (lane >> 4) * 4;
  if (ovals) {
#pragma unroll
    for (int j = 0; j < 4; ++j) {
      int col = wn * 64 + j * 16 + lrow;
      if (col < ACTD) {
        float bv = bias1[col];
#pragma unroll
        for (int i = 0; i < 4; ++i) {
#pragma unroll
          for (int r = 0; r < 4; ++r) {
            size_t row = m0 + wm * 64 + i * 16 + crow0 + r;
            float mv = (float)omask[row];
            ovals[row * ACTD + col] = (acc[i][j][r] + bv) * mv;
          }
        }
      }
    }
    return;
  }
#pragma unroll
  for (int j = 0; j < 4; ++j) {
    int col = (int)n0 + wn * 64 + j * 16 + lrow;
    float bv = bias1 ? bias1[col] : 0.f;
#pragma unroll
    for (int i = 0; i < 4; ++i) {
#pragma unroll
      for (int r = 0; r < 4; ++r) {
        size_t row = m0 + wm * 64 + i * 16 + crow0 + r;
        float v = acc[i][j][r] + bv;
        if (relu) v = fmaxf(v, 0.f);
        C[row * (size_t)N + col] = f2bf(v);
      }
    }
  }
}

// ---------------- 256x256 8-wave double-buffered GEMM (r12-proven) ----------------
__global__ __launch_bounds__(512, 2) void gemm256_kernel(
    const ushort* __restrict__ A, const ushort* __restrict__ Bt,
    const float* __restrict__ bias,
    ushort* __restrict__ C, int M, int N, int K, int relu)
{
  __shared__ __align__(16) ushort lds[2][2][16384];   // [buf][A/B][256*64] = 128 KB

  const int tid  = threadIdx.x;
  const int lane = tid & 63;
  const int wid  = tid >> 6;            // 0..7
  const int wm   = wid >> 2, wn = wid & 3;
  const int nwg  = gridDim.x;           // multiple of 8
  const int q8   = nwg >> 3;
  const int bid  = (blockIdx.x & 7) * q8 + (blockIdx.x >> 3);   // XCD swizzle
  const int ntiles = N >> 8;
  const int bm = bid / ntiles, bn = bid % ntiles;
  const size_t m0 = (size_t)bm << 8, n0 = (size_t)bn << 8;

  const int lrow = lane & 15;
  const int lkg  = lane >> 4;

  int srow[4], sgsr[4];
#pragma unroll
  for (int q = 0; q < 4; ++q) {
    int s = (q * 8 + wid) * 64 + lane;
    srow[q] = s >> 3;
    sgsr[q] = (s & 7) ^ ((s >> 3) & 7);
  }

#define STAGE256(BUF, KT) do {                                                \
    const size_t kb_ = (size_t)(KT) * 64;                                     \
    _Pragma("unroll")                                                         \
    for (int q = 0; q < 4; ++q) {                                             \
      gl_lds16(A  + (m0 + srow[q]) * (size_t)K + kb_ + sgsr[q] * 8,           \
               &lds[BUF][0][(q * 8 + wid) * 512]);                            \
      gl_lds16(Bt + (n0 + srow[q]) * (size_t)K + kb_ + sgsr[q] * 8,           \
               &lds[BUF][1][(q * 8 + wid) * 512]);                            \
    }                                                                         \
  } while (0)

  f32x4_t acc[8][4];
  const f32x4_t zero = {0.f, 0.f, 0.f, 0.f};
#pragma unroll
  for (int f = 0; f < 8; ++f)
#pragma unroll
    for (int n = 0; n < 4; ++n) acc[f][n] = zero;

  const int nkt = K >> 6;
  STAGE256(0, 0);
  STAGE256(1, 1);

  for (int kt = 0; kt < nkt; ++kt) {
    const int buf = kt & 1;
    if (kt + 1 < nkt) WAITVM(8); else WAITVM(0);   // K-tile kt resident
    __builtin_amdgcn_s_barrier();
    __builtin_amdgcn_sched_barrier(0);
#pragma unroll
    for (int p = 0; p < 4; ++p) {
      const int kk = p >> 1, mg = p & 1;
      bf16x8_t av[4], bv[4];
#pragma unroll
      for (int f = 0; f < 4; ++f) {
        int ar = wm * 128 + (mg * 4 + f) * 16 + lrow;
        int ags = (kk * 4 + lkg) ^ (ar & 7);
        av[f] = *(const bf16x8_t*)&lds[buf][0][ar * 64 + ags * 8];
      }
#pragma unroll
      for (int n = 0; n < 4; ++n) {
        int br = wn * 64 + n * 16 + lrow;
        int bgs = (kk * 4 + lkg) ^ (br & 7);
        bv[n] = *(const bf16x8_t*)&lds[buf][1][br * 64 + bgs * 8];
      }
      __builtin_amdgcn_s_setprio(1);
#pragma unroll
      for (int f = 0; f < 4; ++f)
#pragma unroll
        for (int n = 0; n < 4; ++n)
          acc[mg * 4 + f][n] = mfma16(av[f], bv[n], acc[mg * 4 + f][n]);
      __builtin_amdgcn_s_setprio(0);
    }
    __builtin_amdgcn_s_barrier();        // all waves done reading buf
    if (kt + 2 < nkt) STAGE256(buf, kt + 2);
  }
#undef STAGE256

  const int crow0 = lkg * 4;
#pragma unroll
  for (int n = 0; n < 4; ++n) {
    int col = (int)n0 + wn * 64 + n * 16 + lrow;
    float bvv = bias ? bias[col] : 0.f;
#pragma unroll
    for (int f = 0; f < 8; ++f) {
#pragma unroll
      for (int r = 0; r < 4; ++r) {
        size_t row = m0 + (size_t)wm * 128 + f * 16 + crow0 + r;
        float v = acc[f][n][r] + bvv;
        if (relu) v = fmaxf(v, 0.f);
        C[row * (size_t)N + col] = f2bf(v);
      }
    }
  }
}

// ---------------- persistent LSTM scan, eighth-per-WG (r14 — measured optimum) ----------------
// 512 WGs = 8 batch-eighths (16 rows) x 64 j-slices (16 hidden). LDS ~33 KB ->
// 2 WGs/CU co-resident from different eighths: decoupled TLP overlaps the two
// exchange chains (r13's coupled pairing and r15's 128-WG split both regressed).
// Per step: stage-all (8 loads) -> counted-vmcnt chunk consume -> epilogue ->
// LDS bounce -> coherent 8B stores to hseq[t] (unique addr, sc0|sc1, no fence) ->
// flag -> poll (overlapped with xg prefetch) -> syncthreads.
__global__ __launch_bounds__(256, 2) void lstm_scan_kernel(
    const ushort* __restrict__ xg,      // (nsteps,B,4H) bf16, gate-permuted
    const ushort* __restrict__ whh,     // (4H,H) bf16 natural
    const int* __restrict__ mask,       // (nsteps,B) (pre-offset)
    const ushort* __restrict__ hinit,   // (B,H) bf16 zeros (h at t=-1)
    ushort* __restrict__ hseq,          // (T,B,H) bf16: h(t) = latent
    float* __restrict__ cbuf,           // (B,H) f32 persistent cell state
    float* __restrict__ outh, float* __restrict__ outc,   // (B,H) f32
    unsigned* __restrict__ flags,       // 512 x 16 uints, zeroed per launch
    int t0, int nsteps)
{
  __shared__ __align__(16) ushort pool[16 * 1024];  // 32 KB: W gather window, then 8x4KB staging
  __shared__ __align__(16) ushort hexch[16 * 16];   // 0.5 KB h bounce

  const int tid  = threadIdx.x;
  const int lane = tid & 63;
  const int w    = tid >> 6;
  const int wg   = blockIdx.x;
  const int eg   = wg >> 6;            // batch eighth 0..7
  const int jg   = wg & 63;            // j slice
  const int j0   = jg * JG;
  const int b0   = eg * 16;

  const int lrow = lane & 15;
  const int lkg  = lane >> 4;

  // ---- W gather: 4 passes of 16 gate rows through the 32 KB window ----
  bf16x8_t af[8][4];
#pragma unroll 1
  for (int p = 0; p < 4; ++p) {
    for (int c = tid; c < 16 * 128; c += 256) {
      int rl = c >> 7, gn = c & 127;
      int rr = p * 16 + rl;
      int jj = rr >> 2, g = rr & 3;
      const ushort* src = whh + ((size_t)g * HID + j0 + jj) * HID + gn * 8;
      int gnd = (gn & ~7) | ((gn & 7) ^ (rl & 7));
      *reinterpret_cast<uint4*>(&pool[rl * 1024 + gnd * 8]) =
          *reinterpret_cast<const uint4*>(src);
    }
    __syncthreads();
    if (w == p) {
#pragma unroll
      for (int kc = 0; kc < 8; ++kc)
#pragma unroll
        for (int ks = 0; ks < 4; ++ks) {
          int gA = kc * 16 + ks * 4 + lkg;
          int gAs = (gA & ~7) | ((gA & 7) ^ (lrow & 7));
          af[kc][ks] = *(const bf16x8_t*)(pool + (size_t)lrow * 1024 + gAs * 8);
        }
    }
    __syncthreads();
  }

  // cell mapping: thread owns (batch row bl0 = lrow, hidden jjc = w*4+lkg)
  const int jjc = w * 4 + lkg;
  const int bl0 = lrow;

  float creg;
  if (t0 == 0) creg = 0.f;
  else creg = cbuf[(size_t)(b0 + bl0) * HID + j0 + jjc];

  // staging constants: slot s = w*64+lane -> row sb = s>>4, granule sq = s&15
  const int sb = w * 4 + (lane >> 4);
  const int sq = lane & 15;
  const int gg = (sq & 8) | ((sq & 7) ^ (sb & 7));   // swizzle-inverse source granule

  // per-eighth flags: wave0 lane i polls flag (eg*64 + i)
  unsigned* myflag = flags + (size_t)(eg * 64 + jg) * 16;
  const unsigned* fpoll = flags + (size_t)(eg * 64 + lane) * 16;

  // prefetch xg/mask for step 0
  ushort4 xv;
  float mv;
  {
    xv = *(const ushort4*)(xg + (size_t)(b0 + bl0) * GH + (j0 + jjc) * 4);
    mv = (float)mask[b0 + bl0];
  }
  __builtin_amdgcn_sched_barrier(0);

#define CHUNK(KC) do {                                                         \
    WAITVM(7 - (KC));                                                          \
    __builtin_amdgcn_s_barrier();                                              \
    __builtin_amdgcn_sched_barrier(0);                                         \
    const ushort* sbuf = pool + (size_t)(KC) * 2048;                           \
    _Pragma("unroll")                                                          \
    for (int ks = 0; ks < 4; ++ks) {                                           \
      int q16 = ks * 4 + lkg;                                                  \
      int qs = (q16 & 8) | ((q16 & 7) ^ (bl0 & 7));                            \
      bf16x8_t bv = *(const bf16x8_t*)(sbuf + (size_t)bl0 * 128 + qs * 8);     \
      acc = mfma16(af[KC][ks], bv, acc);                                       \
    }                                                                          \
    __builtin_amdgcn_sched_barrier(0);                                         \
  } while (0)

  for (int tl = 0; tl < nsteps; ++tl) {
    const int gs = t0 + tl;
    const ushort* hsrc = (gs == 0)
        ? (hinit + (size_t)b0 * HID)
        : (hseq + (size_t)(gs - 1) * (BATCH * HID) + (size_t)b0 * HID);

    wait_vm0();                          // clean vmcnt slate (prefetch drained)
    __builtin_amdgcn_sched_barrier(0);

    f32x4_t acc = {0.f, 0.f, 0.f, 0.f};

    // issue all 8 cached staging loads back-to-back
#pragma unroll
    for (int kc = 0; kc < 8; ++kc)
      gl_lds16(hsrc + (size_t)sb * HID + (kc * 16 + gg) * 8,
               pool + (size_t)kc * 2048 + (size_t)w * 512);
    __builtin_amdgcn_sched_barrier(0);

    CHUNK(0); CHUNK(1); CHUNK(2); CHUNK(3);
    CHUNK(4); CHUNK(5); CHUNK(6); CHUNK(7);

    // ---- epilogue: fragment-native nonlinearities (thread owns 1 cell) ----
    {
      float ig = sigm(acc[0] + bf2f(xv.x));
      float fg = sigm(acc[1] + bf2f(xv.y));
      float gt = tanhf_fast(acc[2] + bf2f(xv.z));
      float og = sigm(acc[3] + bf2f(xv.w));
      float cp = fg * creg + ig * gt;
      creg = cp * mv;
      float h = og * tanhf_fast(cp) * mv;
      hexch[bl0 * 16 + jjc] = f2bf(h);
      if (gs == T_STEPS - 1) {
        outh[(size_t)(b0 + bl0) * HID + j0 + jjc] = h;
        outc[(size_t)(b0 + bl0) * HID + j0 + jjc] = creg;
      }
    }
    __syncthreads();                     // hexch complete; pool reads done

    // device-coherent 8B h stores into hseq[t] (write-through LLC, no fence)
    if (tid < 64) {
      int bl = tid >> 2, seg = tid & 3;
      unsigned long long v = *(const unsigned long long*)(&hexch[bl * 16 + seg * 4]);
      unsigned long long* dst = (unsigned long long*)(hseq +
          (size_t)gs * (BATCH * HID) + (size_t)(b0 + bl) * HID + j0 + seg * 4);
      __hip_atomic_store(dst, v, __ATOMIC_RELAXED, __HIP_MEMORY_SCOPE_AGENT);
    }

    // ---- per-eighth flat depth-1 barrier (skip after last local step) ----
    if (tl != nsteps - 1) {
      __syncthreads();                   // all h stores complete (vmcnt0/wave)
      const unsigned tgt = (unsigned)(gs + 1);
      if (tid == 0)
        __hip_atomic_store(myflag, tgt, __ATOMIC_RELAXED, __HIP_MEMORY_SCOPE_AGENT);
      // overlap: prefetch next step's xg + mask (immutable -> staleness ok)
      {
        const ushort* xp = xg + (size_t)(tl + 1) * BATCH * GH;
        xv = *(const ushort4*)(xp + (size_t)(b0 + bl0) * GH + (j0 + jjc) * 4);
        mv = (float)mask[(tl + 1) * BATCH + b0 + bl0];
      }
      __builtin_amdgcn_sched_barrier(0);
      // wave0: lane i polls its eighth's flag i (64 flags, one LLC trip/sweep)
      if (tid < 64) {
        for (;;) {
          unsigned v = __hip_atomic_load(fpoll, __ATOMIC_RELAXED, __HIP_MEMORY_SCOPE_AGENT);
          if (__all(v >= tgt)) break;
        }
      }
      __syncthreads();
    }
  }
#undef CHUNK

  // persist cell state for next chunk
  cbuf[(size_t)(b0 + bl0) * HID + j0 + jjc] = creg;
}

extern "C" void kernel_launch(void* const* d_in, const int* in_sizes, int n_in,
                              void* d_out, int out_size, void* d_ws, size_t ws_size,
                              hipStream_t stream) {
  (void)in_sizes; (void)n_in; (void)out_size;
  const float* state = (const float*)d_in[0];
  const int*   mask  = (const int*)d_in[1];
  const float* Wenc  = (const float*)d_in[2];
  const float* benc  = (const float*)d_in[3];
  const float* Wih   = (const float*)d_in[4];
  const float* Whh   = (const float*)d_in[5];
  const float* bih   = (const float*)d_in[6];
  const float* bhh   = (const float*)d_in[7];
  const float* Wdec  = (const float*)d_in[8];
  const float* bdec  = (const float*)d_in[9];

  float* out_values = (float*)d_out;                       // T*B*A
  float* out_h = out_values + (size_t)TBROWS * ACTD;       // B*H
  float* out_c = out_h + (size_t)BATCH * HID;              // B*H

  auto pad256 = [](size_t b) { return (b + 255) & ~(size_t)255; };

  const size_t sz_wenc  = (size_t)HID * OBSD * 2;
  const size_t sz_wih   = (size_t)GH * HID * 2;
  const size_t sz_whh   = (size_t)GH * HID * 2;
  const size_t sz_wdec  = (size_t)128 * HID * 2;
  const size_t sz_bdec  = 512;
  const size_t sz_bperm = (size_t)GH * sizeof(float);
  const size_t sz_flags = (size_t)SNWG * 16 * sizeof(unsigned);   // 32 KB
  const size_t sz_hseq  = (size_t)TBROWS * HID * 2;        // 64 MiB: h(t) = latent
  const size_t sz_hinit = (size_t)BATCH * HID * 2;         // zeros
  const size_t sz_cbuf  = (size_t)BATCH * HID * 4;
  const size_t fixed = pad256(sz_wenc) + pad256(sz_wih) + pad256(sz_whh) +
                       pad256(sz_wdec) + pad256(sz_bdec) + pad256(sz_bperm) +
                       pad256(sz_flags) + pad256(sz_hseq) + pad256(sz_hinit) +
                       pad256(sz_cbuf);

  // largest Tc that fits; state_c aliases xg_c (lifetimes disjoint)
  int Tc = 8;
  {
    const int cands[6] = {256, 128, 64, 32, 16, 8};
    for (int ci = 0; ci < 6; ++ci) {
      int tc = cands[ci];
      size_t per = pad256((size_t)tc * BATCH * HID * 2)       // enc chunk
                 + pad256((size_t)tc * BATCH * GH * 2);       // xg chunk (aliases state)
      if (fixed + per <= ws_size) { Tc = tc; break; }
    }
  }
  const int nchunks = T_STEPS / Tc;
  const int crows = Tc * BATCH;

  char* ws = (char*)d_ws;
  size_t off = 0;
  auto alloc = [&](size_t b) { char* r = ws + off; off += pad256(b); return r; };
  ushort* wenc_bf  = (ushort*)alloc(sz_wenc);
  ushort* wih_perm = (ushort*)alloc(sz_wih);
  ushort* whh_bf   = (ushort*)alloc(sz_whh);
  ushort* wdec_pad = (ushort*)alloc(sz_wdec);
  float*  bdec_pad = (float*)alloc(sz_bdec);
  float*  bperm    = (float*)alloc(sz_bperm);
  unsigned* flags  = (unsigned*)alloc(sz_flags);
  ushort* hseq     = (ushort*)alloc(sz_hseq);
  ushort* hinit    = (ushort*)alloc(sz_hinit);
  float*  cbuf     = (float*)alloc(sz_cbuf);
  ushort* enc_c    = (ushort*)alloc((size_t)crows * HID * 2);
  ushort* xg_c     = (ushort*)alloc((size_t)crows * GH * 2);
  ushort* state_c  = xg_c;               // alias: dead before xg GEMM writes

  hipMemsetAsync(hinit, 0, sz_hinit, stream);
  hipMemsetAsync(flags, 0, sz_flags, stream);
  hipMemsetAsync(wdec_pad, 0, sz_wdec, stream);
  hipMemsetAsync(bdec_pad, 0, sz_bdec, stream);
  hipMemcpyAsync(bdec_pad, bdec, ACTD * sizeof(float), hipMemcpyDeviceToDevice, stream);

  auto cast = [&](const float* src, ushort* dst, size_t n) {
    int n4 = (int)(n / 4);
    int blocks = (n4 + 255) / 256;
    if (blocks > 4096) blocks = 4096;
    cast_bf16_kernel<<<blocks, 256, 0, stream>>>(src, dst, n4);
  };
  cast(Wenc, wenc_bf, (size_t)HID * OBSD);
  cast(Whh, whh_bf, (size_t)GH * HID);
  cast(Wdec, wdec_pad, (size_t)ACTD * HID);
  cast_permute_wih_kernel<<<(GH * 128) / 256, 256, 0, stream>>>(Wih, wih_perm);
  bias_perm_kernel<<<GH / 256, 256, 0, stream>>>(bih, bhh, bperm);

  for (int c = 0; c < nchunks; ++c) {
    const int t0 = c * Tc;
    cast(state + (size_t)t0 * BATCH * OBSD, state_c, (size_t)crows * OBSD);
    // encode: relu(state @ Wenc^T + b_enc)  [256^2 8-wave GEMM]
    gemm256_kernel<<<(crows / 256) * (HID / 256), 512, 0, stream>>>(
        state_c, wenc_bf, benc, enc_c, crows, HID, OBSD, 1);
    // x-gates (gate-permuted cols): enc @ Wih_perm^T + bperm  [256^2 8-wave GEMM]
    gemm256_kernel<<<(crows / 256) * (GH / 256), 512, 0, stream>>>(
        enc_c, wih_perm, bperm, xg_c, crows, GH, HID, 0);
    // sequential scan over this chunk (writes hseq[t0 .. t0+Tc))
    lstm_scan_kernel<<<SNWG, 256, 0, stream>>>(
        xg_c, whh_bf, mask + (size_t)t0 * BATCH, hinit, hseq, cbuf,
        out_h, out_c, flags, t0, Tc);
  }

  // single full-machine decode + mask + extract over ALL timesteps (grid = 256)
  gemm_bt_kernel<<<TBROWS / 128, 256, 0, stream>>>(
      hseq, wdec_pad, bdec_pad, nullptr, TBROWS, 128, HID, 0,
      mask, out_values);
}